// Round 1
// baseline (148.099 us; speedup 1.0000x reference)
//
#include <hip/hip_runtime.h>

namespace {
constexpr int A_N = 96;
constexpr int U_N = 128;
constexpr int V_N = 128;
constexpr int W_N = 128;
constexpr int H_N = 128;
constexpr int NSTEPS = 128;
// T = 0.5*sqrt((127*1)^2 + (127*1)^2) computed in float64, then used as f32
constexpr float T_HALF = 89.80256121069154f;
constexpr float DT = 1.4031650189170554f;  // 2*T/NSTEPS
constexpr int RAYS_PER_BLOCK = 8;
}

__global__ __launch_bounds__(256) void joseph_fwd(
    const float* __restrict__ vol,      // (W,H,D) row-major: vol[x*H*D + y*D + z]
    const float* __restrict__ angles,   // (A)
    float* __restrict__ out)            // (U,A,V) row-major
{
    const int zq  = threadIdx.x & 31;   // 32 quads of 4 z-values = 128 z
    const int r   = threadIdx.x >> 5;   // ray within block (0..7)
    const int u_i = blockIdx.x * RAYS_PER_BLOCK + r;
    const int a   = blockIdx.y;

    const float ang = angles[a];
    const float c = cosf(ang);
    const float s = sinf(ang);
    const float u = (float)u_i - 63.5f;
    // x_idx = -u*sin + t*cos + 63.5 ;  y_idx = u*cos + t*sin + 63.5
    const float xb = fmaf(-u, s, 63.5f);
    const float yb = fmaf( u, c, 63.5f);

    const float* volz = vol + 4 * zq;   // this lane's z offset
    float4 acc = make_float4(0.f, 0.f, 0.f, 0.f);

    for (int i = 0; i < NSTEPS; ++i) {
        const float t  = fmaf((float)i + 0.5f, DT, -T_HALF);
        const float xi = fmaf(t, c, xb);
        const float yi = fmaf(t, s, yb);

        const float fx0f = floorf(xi);
        const float fy0f = floorf(yi);
        const int x0 = (int)fx0f;
        const int y0 = (int)fy0f;
        const float fx = xi - fx0f;
        const float fy = yi - fy0f;
        const int x1 = x0 + 1;
        const int y1 = y0 + 1;

        const float wx0 = (x0 >= 0 && x0 < W_N) ? (1.f - fx) : 0.f;
        const float wx1 = (x1 >= 0 && x1 < W_N) ? fx : 0.f;
        const float wy0 = (y0 >= 0 && y0 < H_N) ? (1.f - fy) : 0.f;
        const float wy1 = (y1 >= 0 && y1 < H_N) ? fy : 0.f;

        // zero-padding: if the sample is fully outside in x or y it contributes 0
        if ((wx0 + wx1) == 0.f || (wy0 + wy1) == 0.f) continue;

        const int cx0 = min(max(x0, 0), W_N - 1);
        const int cx1 = min(max(x1, 0), W_N - 1);
        const int cy0 = min(max(y0, 0), H_N - 1);
        const int cy1 = min(max(y1, 0), H_N - 1);

        const float4 v00 = *(const float4*)(volz + ((cx0 * H_N + cy0) << 7));
        const float4 v01 = *(const float4*)(volz + ((cx1 * H_N + cy0) << 7));
        const float4 v10 = *(const float4*)(volz + ((cx0 * H_N + cy1) << 7));
        const float4 v11 = *(const float4*)(volz + ((cx1 * H_N + cy1) << 7));

        const float w00 = wx0 * wy0;
        const float w01 = wx1 * wy0;
        const float w10 = wx0 * wy1;
        const float w11 = wx1 * wy1;

        acc.x = fmaf(w00, v00.x, fmaf(w01, v01.x, fmaf(w10, v10.x, fmaf(w11, v11.x, acc.x))));
        acc.y = fmaf(w00, v00.y, fmaf(w01, v01.y, fmaf(w10, v10.y, fmaf(w11, v11.y, acc.y))));
        acc.z = fmaf(w00, v00.z, fmaf(w01, v01.z, fmaf(w10, v10.z, fmaf(w11, v11.z, acc.z))));
        acc.w = fmaf(w00, v00.w, fmaf(w01, v01.w, fmaf(w10, v10.w, fmaf(w11, v11.w, acc.w))));
    }

    float4 res = make_float4(acc.x * DT, acc.y * DT, acc.z * DT, acc.w * DT);
    *(float4*)(out + (u_i * A_N + a) * V_N + 4 * zq) = res;
}

extern "C" void kernel_launch(void* const* d_in, const int* in_sizes, int n_in,
                              void* d_out, int out_size, void* d_ws, size_t ws_size,
                              hipStream_t stream) {
    const float* vol    = (const float*)d_in[0];
    const float* angles = (const float*)d_in[1];
    float* out          = (float*)d_out;

    dim3 grid(U_N / RAYS_PER_BLOCK, A_N);
    dim3 block(256);
    hipLaunchKernelGGL(joseph_fwd, grid, block, 0, stream, vol, angles, out);
}

// Round 2
// 136.319 us; speedup vs baseline: 1.0864x; 1.0864x over previous
//
#include <hip/hip_runtime.h>

namespace {
constexpr int A_N = 96;
constexpr int U_N = 128;
constexpr int V_N = 128;
constexpr int W_N = 128;
constexpr int H_N = 128;
constexpr int NSTEPS = 128;
constexpr float T_HALF = 89.80256121069154f;
constexpr float DT = 1.4031650189170554f;  // 2*T/NSTEPS
constexpr int RAYS_PER_BLOCK = 16;         // ZT=8: 16 lanes/ray, 16 rays/block
}

__global__ __launch_bounds__(256) void joseph_fwd(
    const float* __restrict__ vol,      // (W,H,D) row-major: vol[x*H*D + y*D + z]
    const float* __restrict__ angles,   // (A)
    float* __restrict__ out)            // (U,A,V) row-major
{
    const int zo  = threadIdx.x & 15;   // 16 groups of 8 z-values = 128 z
    const int r   = threadIdx.x >> 4;   // ray within block (0..15)
    const int u_i = blockIdx.x * RAYS_PER_BLOCK + r;
    const int a   = blockIdx.y;

    const float ang = angles[a];
    const float c = cosf(ang);
    const float s = sinf(ang);
    const float u = (float)u_i - 63.5f;
    // x_idx = -u*sin + t*cos + 63.5 ;  y_idx = u*cos + t*sin + 63.5
    const float xb = fmaf(-u, s, 63.5f);
    const float yb = fmaf( u, c, 63.5f);

    const float* volz = vol + 8 * zo;   // this lane's z offset (8 contiguous floats)
    float4 accA = make_float4(0.f, 0.f, 0.f, 0.f);
    float4 accB = make_float4(0.f, 0.f, 0.f, 0.f);

    for (int i = 0; i < NSTEPS; ++i) {
        const float t  = fmaf((float)i + 0.5f, DT, -T_HALF);
        const float xi = fmaf(t, c, xb);
        const float yi = fmaf(t, s, yb);

        const float fx0f = floorf(xi);
        const float fy0f = floorf(yi);
        const int x0 = (int)fx0f;
        const int y0 = (int)fy0f;
        const float fx = xi - fx0f;
        const float fy = yi - fy0f;
        const int x1 = x0 + 1;
        const int y1 = y0 + 1;

        const float wx0 = (x0 >= 0 && x0 < W_N) ? (1.f - fx) : 0.f;
        const float wx1 = (x1 >= 0 && x1 < W_N) ? fx : 0.f;
        const float wy0 = (y0 >= 0 && y0 < H_N) ? (1.f - fy) : 0.f;
        const float wy1 = (y1 >= 0 && y1 < H_N) ? fy : 0.f;

        // zero-padding: fully-outside sample contributes 0 (skip is ~uniform
        // across the 4 adjacent-u rays sharing a wave)
        if ((wx0 + wx1) == 0.f || (wy0 + wy1) == 0.f) continue;

        const int cx0 = min(max(x0, 0), W_N - 1);
        const int cx1 = min(max(x1, 0), W_N - 1);
        const int cy0 = min(max(y0, 0), H_N - 1);
        const int cy1 = min(max(y1, 0), H_N - 1);

        const float* p00 = volz + ((cx0 * H_N + cy0) << 7);
        const float* p01 = volz + ((cx1 * H_N + cy0) << 7);
        const float* p10 = volz + ((cx0 * H_N + cy1) << 7);
        const float* p11 = volz + ((cx1 * H_N + cy1) << 7);

        const float4 v00a = *(const float4*)(p00);
        const float4 v00b = *(const float4*)(p00 + 4);
        const float4 v01a = *(const float4*)(p01);
        const float4 v01b = *(const float4*)(p01 + 4);
        const float4 v10a = *(const float4*)(p10);
        const float4 v10b = *(const float4*)(p10 + 4);
        const float4 v11a = *(const float4*)(p11);
        const float4 v11b = *(const float4*)(p11 + 4);

        const float w00 = wx0 * wy0;
        const float w01 = wx1 * wy0;
        const float w10 = wx0 * wy1;
        const float w11 = wx1 * wy1;

        accA.x = fmaf(w00, v00a.x, fmaf(w01, v01a.x, fmaf(w10, v10a.x, fmaf(w11, v11a.x, accA.x))));
        accA.y = fmaf(w00, v00a.y, fmaf(w01, v01a.y, fmaf(w10, v10a.y, fmaf(w11, v11a.y, accA.y))));
        accA.z = fmaf(w00, v00a.z, fmaf(w01, v01a.z, fmaf(w10, v10a.z, fmaf(w11, v11a.z, accA.z))));
        accA.w = fmaf(w00, v00a.w, fmaf(w01, v01a.w, fmaf(w10, v10a.w, fmaf(w11, v11a.w, accA.w))));
        accB.x = fmaf(w00, v00b.x, fmaf(w01, v01b.x, fmaf(w10, v10b.x, fmaf(w11, v11b.x, accB.x))));
        accB.y = fmaf(w00, v00b.y, fmaf(w01, v01b.y, fmaf(w10, v10b.y, fmaf(w11, v11b.y, accB.y))));
        accB.z = fmaf(w00, v00b.z, fmaf(w01, v01b.z, fmaf(w10, v10b.z, fmaf(w11, v11b.z, accB.z))));
        accB.w = fmaf(w00, v00b.w, fmaf(w01, v01b.w, fmaf(w10, v10b.w, fmaf(w11, v11b.w, accB.w))));
    }

    float* op = out + (u_i * A_N + a) * V_N + 8 * zo;
    *(float4*)(op)     = make_float4(accA.x * DT, accA.y * DT, accA.z * DT, accA.w * DT);
    *(float4*)(op + 4) = make_float4(accB.x * DT, accB.y * DT, accB.z * DT, accB.w * DT);
}

extern "C" void kernel_launch(void* const* d_in, const int* in_sizes, int n_in,
                              void* d_out, int out_size, void* d_ws, size_t ws_size,
                              hipStream_t stream) {
    const float* vol    = (const float*)d_in[0];
    const float* angles = (const float*)d_in[1];
    float* out          = (float*)d_out;

    dim3 grid(U_N / RAYS_PER_BLOCK, A_N);   // 8 x 96 = 768 blocks = 3 blocks/CU
    dim3 block(256);
    hipLaunchKernelGGL(joseph_fwd, grid, block, 0, stream, vol, angles, out);
}